// Round 4
// baseline (35989.160 us; speedup 1.0000x reference)
//
#include <hip/hip_runtime.h>

// LSTM: B=8192, T=2048, D=1, H=256, C=10
// Persistent: 256 WGs x 512 threads (8 waves = 2/SIMD, 1 WG/CU via LDS).
// amdgpu_waves_per_eu(2,2) -> 256 VGPR/wave budget: whole working set in regs.
// Per step: (32x256)@(256x1024) via v_mfma_f32_16x16x32_f16; wave wv owns
// gate-col slices s0=2wv, s1=2wv+1 (2 x 16 cols x 4 gates).
// Weight residency (8 kk-groups of K=32): kk=0,1 in LDS (128 KB resident),
// kk=2,3 in VGPRs (64 regs), kk=4..7 streamed from L2 into ping-pong reg
// buffers sbA/sbB (64 regs) with consume-then-reissue: prefetch distance
// ~2 kk-groups (>1200 cyc) >> L2 latency. h single LDS buffer (A-frag order),
// raw lgkmcnt-only barriers (2/step) so stream loads cross barriers.
// d_ws: 512 KB fp16 B-frags, byte off = kk*65536 + s*4096 + t*1024 + lane*16.

#define TT 2048
#define HH 256
#define CC 10

typedef _Float16 half8 __attribute__((ext_vector_type(8)));
typedef float float4v __attribute__((ext_vector_type(4)));

// LDS map (bytes)
#define WLDS_OFF  0          // kk=0,1 resident: 131072
#define HF_OFF    131072     // h in MFMA-A-frag order: 16384
#define BW_OFF    147456     // bias[4][256] f32: 4096
#define WW_OFF    151552     // w_x[4][256] f32: 4096
#define XS_OFF    155648     // x_t[32] f32: 128
#define LDS_TOTAL 155776

__device__ __forceinline__ float frcp(float v)  { return __builtin_amdgcn_rcpf(v); }
__device__ __forceinline__ float fex2(float v)  { return __builtin_amdgcn_exp2f(v); }
__device__ __forceinline__ float fsig(float v)  { return frcp(1.0f + fex2(-1.442695040888963f * v)); }
__device__ __forceinline__ float ftanh(float v) { return 2.0f * frcp(1.0f + fex2(-2.885390081777927f * v)) - 1.0f; }

#define BARRIER_LGKM() asm volatile("s_waitcnt lgkmcnt(0)\n\ts_barrier" ::: "memory")

// Pack W_{g,i,f,o}h (fp32 [256][256], row k, col j) into fp16 MFMA B-frag order.
// unit u = ((kk*16+s)*4+t)*64 + lane ; elem j: k = kk*32 + (lane>>4)*8 + j,
// gate t, hidden col j_h = s*16 + (lane&15).
__global__ void pack_weights(const float* __restrict__ Wg, const float* __restrict__ Wi,
                             const float* __restrict__ Wf, const float* __restrict__ Wo,
                             _Float16* __restrict__ wsW) {
    int u = blockIdx.x * blockDim.x + threadIdx.x;   // 32768 units
    int kk = u >> 12, rem = u & 4095;
    int s = rem >> 8, rem2 = rem & 255;
    int t = rem2 >> 6, lane = rem2 & 63;
    int q = lane >> 4, l15 = lane & 15;
    int jh = s * 16 + l15;
    const float* Wsrc = (t == 0) ? Wg : (t == 1) ? Wi : (t == 2) ? Wf : Wo;
    half8 v;
#pragma unroll
    for (int j = 0; j < 8; ++j) {
        int k = kk * 32 + q * 8 + j;
        v[j] = (_Float16)Wsrc[k * HH + jh];
    }
    ((half8*)wsW)[u] = v;
}

struct Grp { half8 f[2][4]; };   // one kk-group for one wave: 2 slices x 4 gates

__device__ __forceinline__ void load_grp(Grp& B, const char* base_kk_lane) {
    // base = wsW + kk*65536 + s0*4096 + lane*16
#pragma unroll
    for (int sp = 0; sp < 2; ++sp)
#pragma unroll
        for (int t = 0; t < 4; ++t)
            B.f[sp][t] = *(const half8*)(base_kk_lane + sp * 4096 + t * 1024);
}

__device__ __forceinline__ void mfma_grp(float4v acc[2][2][4], half8 a0, half8 a1, const Grp& B) {
#pragma unroll
    for (int sp = 0; sp < 2; ++sp)
#pragma unroll
        for (int t = 0; t < 4; ++t) {
            acc[0][sp][t] = __builtin_amdgcn_mfma_f32_16x16x32_f16(a0, B.f[sp][t], acc[0][sp][t], 0, 0, 0);
            acc[1][sp][t] = __builtin_amdgcn_mfma_f32_16x16x32_f16(a1, B.f[sp][t], acc[1][sp][t], 0, 0, 0);
        }
}

__attribute__((amdgpu_waves_per_eu(2, 2)))
__global__ void __launch_bounds__(512) lstm_main(
    const float* __restrict__ x, const _Float16* __restrict__ wsW,
    const float* __restrict__ Wgx, const float* __restrict__ Wix,
    const float* __restrict__ Wfx, const float* __restrict__ Wox,
    const float* __restrict__ bg, const float* __restrict__ bi,
    const float* __restrict__ bfp, const float* __restrict__ bo,
    const float* __restrict__ Wp, const float* __restrict__ bp,
    float* __restrict__ out)
{
    extern __shared__ char smem[];
    _Float16* Wlds = (_Float16*)(smem + WLDS_OFF);
    _Float16* hf   = (_Float16*)(smem + HF_OFF);
    float*    bwL  = (float*)(smem + BW_OFF);
    float*    wwL  = (float*)(smem + WW_OFF);
    float*    xs   = (float*)(smem + XS_OFF);

    const int tid  = threadIdx.x;
    const int wv   = tid >> 6;          // wave 0..7
    const int lane = tid & 63;
    const int q    = lane >> 4;
    const int l15  = lane & 15;
    const int s0   = wv * 2;            // this wave's first col-slice
    const int b0   = blockIdx.x * 32;

    // ---- prologue ----
    for (int i = tid; i < 8192; i += 512) hf[i] = (_Float16)0.f;   // h0 = 0
    {   // stage kk=0,1 into LDS (frag layout preserved)
        const uint4* src = (const uint4*)wsW;
        uint4* dst = (uint4*)Wlds;
        for (int i = tid; i < 131072 / 16; i += 512) dst[i] = src[i];
    }
    {   // stage biases and x-weights
        const float* bptr[4] = { bg, bi, bfp, bo };
        const float* wptr[4] = { Wgx, Wix, Wfx, Wox };
        for (int i = tid; i < 1024; i += 512) {
            int t = i >> 8, j = i & 255;
            bwL[i] = bptr[t][j];
            wwL[i] = wptr[t][j];
        }
    }
    if (tid < 32) xs[tid] = x[(b0 + tid) * TT + 0];

    const char* wl = (const char*)wsW + s0 * 4096 + lane * 16;   // + kk*65536 + sp*4096 + t*1024
    Grp wr2, wr3, sbA, sbB;
    load_grp(wr2, wl + 2 * 65536);
    load_grp(wr3, wl + 3 * 65536);
    load_grp(sbA, wl + 4 * 65536);     // stream prime
    load_grp(sbB, wl + 5 * 65536);

    float4v cst[2][2];
#pragma unroll
    for (int mt = 0; mt < 2; ++mt)
#pragma unroll
        for (int sp = 0; sp < 2; ++sp) cst[mt][sp] = (float4v){0.f, 0.f, 0.f, 0.f};

    // h-write scatter base (A-frag order), j in [32wv, 32wv+32) -> kk' = wv
    const int wb = wv * 512 + ((l15 >> 3) * 16 + q * 4) * 8 + (l15 & 7);  // + mt*4096 + sp*256 + r*8

    __syncthreads();

#define AREAD(kkv, mtv) (*(const half8*)(hf + (mtv) * 4096 + (kkv) * 512 + lane * 8))

    // ---- time loop ----
#pragma unroll 1
    for (int ts = 0; ts < TT; ++ts) {
        // acc init = bias + x_t * W_x (fp32, exact)
        float xv[2][4];
#pragma unroll
        for (int mt = 0; mt < 2; ++mt)
#pragma unroll
            for (int r = 0; r < 4; ++r) xv[mt][r] = xs[mt * 16 + q * 4 + r];
        float4v acc[2][2][4];
#pragma unroll
        for (int sp = 0; sp < 2; ++sp) {
            int jj = (s0 + sp) * 16 + l15;
#pragma unroll
            for (int t = 0; t < 4; ++t) {
                float bb = bwL[t * 256 + jj];
                float wx = wwL[t * 256 + jj];
#pragma unroll
                for (int mt = 0; mt < 2; ++mt)
#pragma unroll
                    for (int r = 0; r < 4; ++r)
                        acc[mt][sp][t][r] = bb + xv[mt][r] * wx;
            }
        }

        // prefetch next x (consumed at step end)
        float xnext = 0.f;
        const int tn = (ts + 1 < TT) ? (ts + 1) : (TT - 1);
        if (tid < 32) xnext = x[(b0 + tid) * TT + tn];

        half8 a0, a1;
        // kk=0,1: B from LDS
#pragma unroll
        for (int kk = 0; kk < 2; ++kk) {
            a0 = AREAD(kk, 0); a1 = AREAD(kk, 1);
            const char* lb = (const char*)Wlds + kk * 65536 + s0 * 4096 + lane * 16;
#pragma unroll
            for (int sp = 0; sp < 2; ++sp)
#pragma unroll
                for (int t = 0; t < 4; ++t) {
                    half8 bf = *(const half8*)(lb + sp * 4096 + t * 1024);
                    acc[0][sp][t] = __builtin_amdgcn_mfma_f32_16x16x32_f16(a0, bf, acc[0][sp][t], 0, 0, 0);
                    acc[1][sp][t] = __builtin_amdgcn_mfma_f32_16x16x32_f16(a1, bf, acc[1][sp][t], 0, 0, 0);
                }
        }
        // kk=2,3: B VGPR-resident
        a0 = AREAD(2, 0); a1 = AREAD(2, 1); mfma_grp(acc, a0, a1, wr2);
        a0 = AREAD(3, 0); a1 = AREAD(3, 1); mfma_grp(acc, a0, a1, wr3);
        // kk=4..7: streamed ping-pong (consume, then reissue 2 groups ahead)
        a0 = AREAD(4, 0); a1 = AREAD(4, 1); mfma_grp(acc, a0, a1, sbA);
        load_grp(sbA, wl + 6 * 65536);
        a0 = AREAD(5, 0); a1 = AREAD(5, 1); mfma_grp(acc, a0, a1, sbB);
        load_grp(sbB, wl + 7 * 65536);
        a0 = AREAD(6, 0); a1 = AREAD(6, 1); mfma_grp(acc, a0, a1, sbA);
        load_grp(sbA, wl + 4 * 65536);     // next step
        a0 = AREAD(7, 0); a1 = AREAD(7, 1); mfma_grp(acc, a0, a1, sbB);
        load_grp(sbB, wl + 5 * 65536);     // next step

        // gates + state update (lane owns rows mt*16+q*4+r, col (s0+sp)*16+l15)
        _Float16 hn[2][2][4];
#pragma unroll
        for (int mt = 0; mt < 2; ++mt)
#pragma unroll
            for (int sp = 0; sp < 2; ++sp)
#pragma unroll
                for (int r = 0; r < 4; ++r) {
                    float g  = ftanh(acc[mt][sp][0][r]);
                    float ii = fsig (acc[mt][sp][1][r]);
                    float f  = fsig (acc[mt][sp][2][r]);
                    float o  = fsig (acc[mt][sp][3][r]);
                    float cn = g * ii + cst[mt][sp][r] * f;
                    cst[mt][sp][r] = cn;
                    hn[mt][sp][r] = (_Float16)(ftanh(cn) * o);
                }

        BARRIER_LGKM();   // B1: all A-reads of old h retired everywhere
#pragma unroll
        for (int mt = 0; mt < 2; ++mt)
#pragma unroll
            for (int sp = 0; sp < 2; ++sp)
#pragma unroll
                for (int r = 0; r < 4; ++r)
                    hf[mt * 4096 + wb + sp * 256 + r * 8] = hn[mt][sp][r];
        if (tid < 32) xs[tid] = xnext;
        BARRIER_LGKM();   // B2: new h visible (stream loads stay in flight)
    }

    // ---- epilogue: out = h_T @ W_ph + b_p ; wave wv handles rows 4wv..4wv+3 ----
#pragma unroll
    for (int rr = 0; rr < 4; ++rr) {
        int b = wv * 4 + rr;
        int mt = b >> 4, m = b & 15;
        float hv[4];
#pragma unroll
        for (int a = 0; a < 4; ++a) {
            int j = lane + a * 64;
            int idx = mt * 4096 + (j >> 5) * 512 + (((j >> 3) & 3) * 16 + m) * 8 + (j & 7);
            hv[a] = (float)hf[idx];
        }
#pragma unroll
        for (int c = 0; c < CC; ++c) {
            float sacc = 0.f;
#pragma unroll
            for (int a = 0; a < 4; ++a) sacc += hv[a] * Wp[(lane + a * 64) * CC + c];
#pragma unroll
            for (int off = 32; off > 0; off >>= 1) sacc += __shfl_xor(sacc, off, 64);
            if (lane == 0) out[(b0 + b) * CC + c] = sacc + bp[c];
        }
    }
}

extern "C" void kernel_launch(void* const* d_in, const int* in_sizes, int n_in,
                              void* d_out, int out_size, void* d_ws, size_t ws_size,
                              hipStream_t stream) {
    (void)in_sizes; (void)n_in; (void)out_size; (void)ws_size; // needs ws_size >= 524288
    const float* x   = (const float*)d_in[0];
    const float* Wgx = (const float*)d_in[1];
    const float* Wgh = (const float*)d_in[2];
    const float* Wix = (const float*)d_in[3];
    const float* Wih = (const float*)d_in[4];
    const float* Wfx = (const float*)d_in[5];
    const float* Wfh = (const float*)d_in[6];
    const float* Wox = (const float*)d_in[7];
    const float* Woh = (const float*)d_in[8];
    const float* Wp  = (const float*)d_in[9];
    const float* bg  = (const float*)d_in[10];
    const float* bi  = (const float*)d_in[11];
    const float* bf  = (const float*)d_in[12];
    const float* bo  = (const float*)d_in[13];
    const float* bp  = (const float*)d_in[14];
    _Float16* wsW = (_Float16*)d_ws;

    pack_weights<<<128, 256, 0, stream>>>(Wgh, Wih, Wfh, Woh, wsW);

    hipFuncSetAttribute((const void*)lstm_main,
                        hipFuncAttributeMaxDynamicSharedMemorySize, LDS_TOTAL);
    lstm_main<<<256, 512, LDS_TOTAL, stream>>>(
        x, wsW, Wgx, Wix, Wfx, Wox, bg, bi, bf, bo, Wp, bp, (float*)d_out);
}

// Round 5
// 23516.969 us; speedup vs baseline: 1.5303x; 1.5303x over previous
//
#include <hip/hip_runtime.h>

// LSTM: B=8192, T=2048, D=1, H=256, C=10
// Persistent: 256 WGs x 512 threads (8 waves, 1 WG/CU), 32 batch rows per WG.
// Per step: (32x256)@(256x1024) via v_mfma_f32_16x16x32_f16.
// wpe(2,2) => 128 arch-VGPR budget + 128 AGPR (proven R4); non-acc VGPR
// demand ~122 (audited), acc (64) in AGPRs -> NO loop-carried spills.
// Weight residency (8 kk-groups of K=32): kk=0,1 LDS-resident (128 KB, read
// as 4-reg transients per MFMA), kk=2..7 reg-streamed via ONE ping-pong pair
// sbA/sbB (64 regs, even/odd parity stable across steps, 2-group prefetch
// distance, compiler-managed vmcnt). x_t: one lane-parallel global load +
// __shfl broadcast + post-K fma (no vmcnt coupling, latency hidden under K).
// h single LDS buffer (A-frag order), 2 lgkm-only barriers/step so stream
// loads stay in flight across barriers.
// d_ws: 512 KB fp16 B-frags, byte off = kk*65536 + s*4096 + t*1024 + lane*16.

#define TT 2048
#define HH 256
#define CC 10

typedef _Float16 half8 __attribute__((ext_vector_type(8)));
typedef float float4v __attribute__((ext_vector_type(4)));

// LDS map (bytes)
#define HF_OFF    131072                 // after 128 KB resident weights
#define LDS_TOTAL (131072 + 16384)       // 147456

__device__ __forceinline__ float frcp(float v)  { return __builtin_amdgcn_rcpf(v); }
__device__ __forceinline__ float fex2(float v)  { return __builtin_amdgcn_exp2f(v); }
__device__ __forceinline__ float fsig(float v)  { return frcp(1.0f + fex2(-1.442695040888963f * v)); }
__device__ __forceinline__ float ftanh(float v) { return 2.0f * frcp(1.0f + fex2(-2.885390081777927f * v)) - 1.0f; }

#define BARRIER_LGKM() asm volatile("s_waitcnt lgkmcnt(0)\n\ts_barrier" ::: "memory")

// Pack W_{g,i,f,o}h (fp32 [256][256], row k, col j) into fp16 MFMA B-frag order.
// unit u = ((kk*16+s)*4+t)*64 + lane ; elem j: k = kk*32 + (lane>>4)*8 + j,
// gate t, hidden col j_h = s*16 + (lane&15).
__global__ void pack_weights(const float* __restrict__ Wg, const float* __restrict__ Wi,
                             const float* __restrict__ Wf, const float* __restrict__ Wo,
                             _Float16* __restrict__ wsW) {
    int u = blockIdx.x * blockDim.x + threadIdx.x;   // 32768 units
    int kk = u >> 12, rem = u & 4095;
    int s = rem >> 8, rem2 = rem & 255;
    int t = rem2 >> 6, lane = rem2 & 63;
    int q = lane >> 4, l15 = lane & 15;
    int jh = s * 16 + l15;
    const float* Wsrc = (t == 0) ? Wg : (t == 1) ? Wi : (t == 2) ? Wf : Wo;
    half8 v;
#pragma unroll
    for (int j = 0; j < 8; ++j) {
        int k = kk * 32 + q * 8 + j;
        v[j] = (_Float16)Wsrc[k * HH + jh];
    }
    ((half8*)wsW)[u] = v;
}

struct Grp { half8 f[2][4]; };   // one kk-group for one wave: 2 slices x 4 gates

__device__ __forceinline__ void load_grp(Grp& B, const char* base) {
    // base = wsW + kk*65536 + s0*4096 + lane*16 ; offsets sp*4096 + t*1024
#pragma unroll
    for (int sp = 0; sp < 2; ++sp)
#pragma unroll
        for (int t = 0; t < 4; ++t)
            B.f[sp][t] = *(const half8*)(base + sp * 4096 + t * 1024);
}

__device__ __forceinline__ void mfma_grp(float4v acc[2][2][4], half8 a0, half8 a1, const Grp& B) {
#pragma unroll
    for (int sp = 0; sp < 2; ++sp)
#pragma unroll
        for (int t = 0; t < 4; ++t) {
            acc[0][sp][t] = __builtin_amdgcn_mfma_f32_16x16x32_f16(a0, B.f[sp][t], acc[0][sp][t], 0, 0, 0);
            acc[1][sp][t] = __builtin_amdgcn_mfma_f32_16x16x32_f16(a1, B.f[sp][t], acc[1][sp][t], 0, 0, 0);
        }
}

__attribute__((amdgpu_waves_per_eu(2, 2)))
__global__ void __launch_bounds__(512) lstm_main(
    const float* __restrict__ x, const _Float16* __restrict__ wsW,
    const float* __restrict__ Wgx, const float* __restrict__ Wix,
    const float* __restrict__ Wfx, const float* __restrict__ Wox,
    const float* __restrict__ bg, const float* __restrict__ bi,
    const float* __restrict__ bfp, const float* __restrict__ bo,
    const float* __restrict__ Wp, const float* __restrict__ bp,
    float* __restrict__ out)
{
    extern __shared__ char smem[];
    char*     WldsC = smem;                       // kk=0,1 resident (layout as d_ws)
    _Float16* hf    = (_Float16*)(smem + HF_OFF); // h, A-frag order

    const int tid  = threadIdx.x;
    const int wv   = tid >> 6;          // wave 0..7
    const int lane = tid & 63;
    const int q    = lane >> 4;
    const int l15  = lane & 15;
    const int s0   = wv * 2;            // this wave's first col-slice
    const int b0   = blockIdx.x * 32;

    // ---- prologue ----
    for (int i = tid; i < 8192; i += 512) hf[i] = (_Float16)0.f;    // h0 = 0
    {   // stage kk=0,1 into LDS (frag layout preserved)
        const uint4* src = (const uint4*)wsW;
        uint4* dst = (uint4*)WldsC;
        for (int i = tid; i < 131072 / 16; i += 512) dst[i] = src[i];
    }
    // per-lane bias / x-weight for owned cols jj=(s0+sp)*16+l15 (16 regs)
    float bv[2][4], wxv[2][4];
    {
        const float* bptr[4] = { bg, bi, bfp, bo };
        const float* wptr[4] = { Wgx, Wix, Wfx, Wox };
#pragma unroll
        for (int sp = 0; sp < 2; ++sp) {
            int jj = (s0 + sp) * 16 + l15;
#pragma unroll
            for (int t = 0; t < 4; ++t) { bv[sp][t] = bptr[t][jj]; wxv[sp][t] = wptr[t][jj]; }
        }
    }
    const char* wl = (const char*)wsW + s0 * 4096 + lane * 16;  // + kk*65536 (+sp*4096 +t*1024)
    Grp sbA, sbB;                                               // stream ping-pong: 64 regs
    load_grp(sbA, wl + 2 * 65536);
    load_grp(sbB, wl + 3 * 65536);

    float4v cst[2][2];
#pragma unroll
    for (int mt = 0; mt < 2; ++mt)
#pragma unroll
        for (int sp = 0; sp < 2; ++sp) cst[mt][sp] = (float4v){0.f, 0.f, 0.f, 0.f};

    // h-write scatter base (A-frag order): col j = 32wv + sp*16 + l15, row mt*16+q*4+r
    const int wb = wv * 512 + ((l15 >> 3) * 16 + q * 4) * 8 + (l15 & 7);  // + mt*4096 + sp*256 + r*8

    __syncthreads();

#define AREAD(kkv, mtv) (*(const half8*)(hf + (mtv) * 4096 + (kkv) * 512 + lane * 8))

    // ---- time loop ----
#pragma unroll 1
    for (int ts = 0; ts < TT; ++ts) {
        // x for this step: lane-parallel load (row = lane&31), consumed post-K
        float xld = x[(b0 + (lane & 31)) * TT + ts];

        float4v acc[2][2][4];
#pragma unroll
        for (int mt = 0; mt < 2; ++mt)
#pragma unroll
            for (int sp = 0; sp < 2; ++sp)
#pragma unroll
                for (int t = 0; t < 4; ++t) acc[mt][sp][t] = (float4v){0.f, 0.f, 0.f, 0.f};

        half8 a0, a1;
        // kk=0,1: B from LDS (4-reg transients per MFMA pair)
#pragma unroll
        for (int kk = 0; kk < 2; ++kk) {
            a0 = AREAD(kk, 0); a1 = AREAD(kk, 1);
            const char* lb = WldsC + kk * 65536 + s0 * 4096 + lane * 16;
#pragma unroll
            for (int sp = 0; sp < 2; ++sp)
#pragma unroll
                for (int t = 0; t < 4; ++t) {
                    half8 bf = *(const half8*)(lb + sp * 4096 + t * 1024);
                    acc[0][sp][t] = __builtin_amdgcn_mfma_f32_16x16x32_f16(a0, bf, acc[0][sp][t], 0, 0, 0);
                    acc[1][sp][t] = __builtin_amdgcn_mfma_f32_16x16x32_f16(a1, bf, acc[1][sp][t], 0, 0, 0);
                }
        }
        // kk=2..7: reg-streamed, even->sbA odd->sbB, reload +2 after consume
        a0 = AREAD(2, 0); a1 = AREAD(2, 1); mfma_grp(acc, a0, a1, sbA);
        load_grp(sbA, wl + 4 * 65536);
        a0 = AREAD(3, 0); a1 = AREAD(3, 1); mfma_grp(acc, a0, a1, sbB);
        load_grp(sbB, wl + 5 * 65536);
        a0 = AREAD(4, 0); a1 = AREAD(4, 1); mfma_grp(acc, a0, a1, sbA);
        load_grp(sbA, wl + 6 * 65536);
        a0 = AREAD(5, 0); a1 = AREAD(5, 1); mfma_grp(acc, a0, a1, sbB);
        load_grp(sbB, wl + 7 * 65536);
        a0 = AREAD(6, 0); a1 = AREAD(6, 1); mfma_grp(acc, a0, a1, sbA);
        load_grp(sbA, wl + 2 * 65536);     // next step
        a0 = AREAD(7, 0); a1 = AREAD(7, 1); mfma_grp(acc, a0, a1, sbB);
        load_grp(sbB, wl + 3 * 65536);     // next step

        // post-K: add bias + x_t * W_x (x broadcast via shuffle, latency hidden)
        float xv[2][4];
#pragma unroll
        for (int mt = 0; mt < 2; ++mt)
#pragma unroll
            for (int r = 0; r < 4; ++r)
                xv[mt][r] = __shfl(xld, mt * 16 + q * 4 + r, 64);
#pragma unroll
        for (int mt = 0; mt < 2; ++mt)
#pragma unroll
            for (int sp = 0; sp < 2; ++sp)
#pragma unroll
                for (int t = 0; t < 4; ++t)
#pragma unroll
                    for (int r = 0; r < 4; ++r)
                        acc[mt][sp][t][r] += bv[sp][t] + xv[mt][r] * wxv[sp][t];

        // gates + state update (lane owns rows mt*16+q*4+r, col (s0+sp)*16+l15)
        _Float16 hn[2][2][4];
#pragma unroll
        for (int mt = 0; mt < 2; ++mt)
#pragma unroll
            for (int sp = 0; sp < 2; ++sp)
#pragma unroll
                for (int r = 0; r < 4; ++r) {
                    float g  = ftanh(acc[mt][sp][0][r]);
                    float ii = fsig (acc[mt][sp][1][r]);
                    float f  = fsig (acc[mt][sp][2][r]);
                    float o  = fsig (acc[mt][sp][3][r]);
                    float cn = g * ii + cst[mt][sp][r] * f;
                    cst[mt][sp][r] = cn;
                    hn[mt][sp][r] = (_Float16)(ftanh(cn) * o);
                }

        BARRIER_LGKM();   // B1: all waves' A-reads of old h retired (lgkm only)
#pragma unroll
        for (int mt = 0; mt < 2; ++mt)
#pragma unroll
            for (int sp = 0; sp < 2; ++sp)
#pragma unroll
                for (int r = 0; r < 4; ++r)
                    hf[mt * 4096 + wb + sp * 256 + r * 8] = hn[mt][sp][r];
        BARRIER_LGKM();   // B2: new h visible; stream loads stay in flight
    }

    // ---- epilogue: out = h_T @ W_ph + b_p ; wave wv handles rows 4wv..4wv+3 ----
#pragma unroll
    for (int rr = 0; rr < 4; ++rr) {
        int b = wv * 4 + rr;
        int mt = b >> 4, m = b & 15;
        float hv[4];
#pragma unroll
        for (int a = 0; a < 4; ++a) {
            int j = lane + a * 64;
            int idx = mt * 4096 + (j >> 5) * 512 + (((j >> 3) & 3) * 16 + m) * 8 + (j & 7);
            hv[a] = (float)hf[idx];
        }
#pragma unroll
        for (int c = 0; c < CC; ++c) {
            float sacc = 0.f;
#pragma unroll
            for (int a = 0; a < 4; ++a) sacc += hv[a] * Wp[(lane + a * 64) * CC + c];
#pragma unroll
            for (int off = 32; off > 0; off >>= 1) sacc += __shfl_xor(sacc, off, 64);
            if (lane == 0) out[(b0 + b) * CC + c] = sacc + bp[c];
        }
    }
}

extern "C" void kernel_launch(void* const* d_in, const int* in_sizes, int n_in,
                              void* d_out, int out_size, void* d_ws, size_t ws_size,
                              hipStream_t stream) {
    (void)in_sizes; (void)n_in; (void)out_size; (void)ws_size; // needs ws_size >= 524288
    const float* x   = (const float*)d_in[0];
    const float* Wgx = (const float*)d_in[1];
    const float* Wgh = (const float*)d_in[2];
    const float* Wix = (const float*)d_in[3];
    const float* Wih = (const float*)d_in[4];
    const float* Wfx = (const float*)d_in[5];
    const float* Wfh = (const float*)d_in[6];
    const float* Wox = (const float*)d_in[7];
    const float* Woh = (const float*)d_in[8];
    const float* Wp  = (const float*)d_in[9];
    const float* bg  = (const float*)d_in[10];
    const float* bi  = (const float*)d_in[11];
    const float* bf  = (const float*)d_in[12];
    const float* bo  = (const float*)d_in[13];
    const float* bp  = (const float*)d_in[14];
    _Float16* wsW = (_Float16*)d_ws;

    pack_weights<<<128, 256, 0, stream>>>(Wgh, Wih, Wfh, Woh, wsW);

    hipFuncSetAttribute((const void*)lstm_main,
                        hipFuncAttributeMaxDynamicSharedMemorySize, LDS_TOTAL);
    lstm_main<<<256, 512, LDS_TOTAL, stream>>>(
        x, wsW, Wgx, Wix, Wfx, Wox, bg, bi, bf, bo, Wp, bp, (float*)d_out);
}

// Round 6
// 12385.419 us; speedup vs baseline: 2.9058x; 1.8988x over previous
//
#include <hip/hip_runtime.h>

// LSTM: B=8192, T=2048, D=1, H=256, C=10
// Persistent: 256 WGs x 512 threads (1/CU), 32 batch rows per WG.
// Per step: (32x256)@(256x1024) via v_mfma_f32_16x16x32_f16.
// NO weights in VGPRs (R1-R5 post-mortem: any weight regs + acc's VALU-phase
// materialization > 128 regs -> loop-invariant scratch spills re-read every
// step = 57-87 GB HBM). kk=0 LDS-resident; kk=1..7 streamed from L2 via
// global_load_lds into a 4-slot x 16 KB LDS ring: per-wave self-staged
// chunks (kk,t), prefetch distance 3, uniform s_waitcnt vmcnt(4) gate;
// the mod-28 chunk stream wraps across steps (weights step-invariant), so
// in-flight DMAs cross the lgkm-only step barriers. x staged to LDS every
// 32 steps; bias/Wx in LDS. Non-acc demand ~50 regs -> no spills even if
// acc is VGPR-materialized. d_ws: 512 KB fp16 B-frags,
// byte off = kk*65536 + s*4096 + t*1024 + lane*16.

#define TT 2048
#define HH 256
#define CC 10

typedef _Float16 half8 __attribute__((ext_vector_type(8)));
typedef float float4v __attribute__((ext_vector_type(4)));

// LDS map (bytes)
#define WRES_OFF  0                      // kk=0 resident: 64 KB
#define RING_OFF  65536                  // 4 slots x 16384
#define RING_SLOT 16384
#define HF_OFF    131072                 // h, A-frag order: 16 KB
#define BW_OFF    147456                 // bias[4][256] f32
#define WW_OFF    151552                 // w_x[4][256] f32
#define XS_OFF    155648                 // x[32 rows][32 steps] f32
#define LDS_TOTAL 159744

__device__ __forceinline__ float frcp(float v)  { return __builtin_amdgcn_rcpf(v); }
__device__ __forceinline__ float fex2(float v)  { return __builtin_amdgcn_exp2f(v); }
__device__ __forceinline__ float fsig(float v)  { return frcp(1.0f + fex2(-1.442695040888963f * v)); }
__device__ __forceinline__ float ftanh(float v) { return 2.0f * frcp(1.0f + fex2(-2.885390081777927f * v)) - 1.0f; }

__device__ __forceinline__ void stream_issue(const void* g, void* l) {
    __builtin_amdgcn_global_load_lds((const __attribute__((address_space(1))) void*)g,
                                     (__attribute__((address_space(3))) void*)l, 16, 0, 0);
}
#define WAIT_VM4()     asm volatile("s_waitcnt vmcnt(4)" ::: "memory")
#define BARRIER_LGKM() asm volatile("s_waitcnt lgkmcnt(0)\n\ts_barrier" ::: "memory")

// Pack W_{g,i,f,o}h (fp32 [256][256], row k, col j) into fp16 MFMA B-frag order.
// unit u = ((kk*16+s)*4+t)*64 + lane ; elem j: k = kk*32 + (lane>>4)*8 + j,
// gate t, hidden col j_h = s*16 + (lane&15).
__global__ void pack_weights(const float* __restrict__ Wg, const float* __restrict__ Wi,
                             const float* __restrict__ Wf, const float* __restrict__ Wo,
                             _Float16* __restrict__ wsW) {
    int u = blockIdx.x * blockDim.x + threadIdx.x;   // 32768 units
    int kk = u >> 12, rem = u & 4095;
    int s = rem >> 8, rem2 = rem & 255;
    int t = rem2 >> 6, lane = rem2 & 63;
    int q = lane >> 4, l15 = lane & 15;
    int jh = s * 16 + l15;
    const float* Wsrc = (t == 0) ? Wg : (t == 1) ? Wi : (t == 2) ? Wf : Wo;
    half8 v;
#pragma unroll
    for (int j = 0; j < 8; ++j) {
        int k = kk * 32 + q * 8 + j;
        v[j] = (_Float16)Wsrc[k * HH + jh];
    }
    ((half8*)wsW)[u] = v;
}

__attribute__((amdgpu_waves_per_eu(2, 2)))
__global__ void __launch_bounds__(512) lstm_main(
    const float* __restrict__ x, const _Float16* __restrict__ wsW,
    const float* __restrict__ Wgx, const float* __restrict__ Wix,
    const float* __restrict__ Wfx, const float* __restrict__ Wox,
    const float* __restrict__ bg, const float* __restrict__ bi,
    const float* __restrict__ bfp, const float* __restrict__ bo,
    const float* __restrict__ Wp, const float* __restrict__ bp,
    float* __restrict__ out)
{
    extern __shared__ char smem[];
    _Float16* hf  = (_Float16*)(smem + HF_OFF);
    float*    bwL = (float*)(smem + BW_OFF);
    float*    wwL = (float*)(smem + WW_OFF);
    float*    xsL = (float*)(smem + XS_OFF);

    const int tid  = threadIdx.x;
    const int wv   = tid >> 6;          // wave 0..7
    const int lane = tid & 63;
    const int q    = lane >> 4;
    const int l15  = lane & 15;
    const int s0   = wv * 2;            // this wave's first col-slice
    const int b0   = blockIdx.x * 32;

    // ---- prologue ----
    for (int i = tid; i < 8192; i += 512) hf[i] = (_Float16)0.f;    // h0 = 0
    {   // stage kk=0 into LDS (frag layout preserved)
        const uint4* src = (const uint4*)wsW;
        uint4* dst = (uint4*)(smem + WRES_OFF);
        for (int i = tid; i < 65536 / 16; i += 512) dst[i] = src[i];
    }
    {   // stage biases and x-weights
        const float* bptr[4] = { bg, bi, bfp, bo };
        const float* wptr[4] = { Wgx, Wix, Wfx, Wox };
        for (int i = tid; i < 1024; i += 512) {
            int t = i >> 8, j = i & 255;
            bwL[i] = bptr[t][j];
            wwL[i] = wptr[t][j];
        }
    }
    __syncthreads();   // full drain BEFORE priming the ring

    // per-lane / per-wave pointers
    const char* wl = (const char*)wsW + s0 * 4096 + lane * 16;  // + kk*65536 + sp*4096 + t*1024
    char* ringW = smem + RING_OFF + wv * 2048;                  // wave-uniform; + slot*16384 + sp*1024
    const _Float16* ringR = (const _Float16*)(smem + RING_OFF) + wv * 1024 + lane * 8;

    // prime ring: chunks m=0,1,2 (kk=1+(m>>2), t=m&3), slot = m&3
#pragma unroll
    for (int m = 0; m < 3; ++m) {
        const int kk = 1 + (m >> 2), t = m & 3;
#pragma unroll
        for (int sp = 0; sp < 2; ++sp)
            stream_issue(wl + kk * 65536 + sp * 4096 + t * 1024,
                         ringW + (m & 3) * RING_SLOT + sp * 1024);
    }

    float4v cst[2][2];
#pragma unroll
    for (int mt = 0; mt < 2; ++mt)
#pragma unroll
        for (int sp = 0; sp < 2; ++sp) cst[mt][sp] = (float4v){0.f, 0.f, 0.f, 0.f};

    // h-write scatter base (A-frag order): col j = 32wv+sp*16+l15, row mt*16+q*4+r
    const int wb = wv * 512 + ((l15 >> 3) * 16 + q * 4) * 8 + (l15 & 7);  // + mt*4096 + sp*256 + r*8

#define AREAD(kkv, mtv) (*(const half8*)(hf + (mtv) * 4096 + (kkv) * 512 + lane * 8))

    // ---- time loop ----
#pragma unroll 1
    for (int ts = 0; ts < TT; ++ts) {
        // x staging: once per 32 steps (the compiler's vmcnt drain here is the
        // only ring-drain; amortized ~35 cyc/step)
        if ((ts & 31) == 0) {
            const int row = tid >> 4;            // 0..31
            const int c2  = (tid & 15) * 2;      // 0,2,..,30
            float2 xv2 = *(const float2*)&x[(b0 + row) * TT + ts + c2];
            *(float2*)&xsL[row * 32 + c2] = xv2;
            BARRIER_LGKM();
        }

        // acc init = bias + x_t * W_x (fp32, exact; all operands from LDS)
        float xv[2][4];
#pragma unroll
        for (int mt = 0; mt < 2; ++mt)
#pragma unroll
            for (int r = 0; r < 4; ++r)
                xv[mt][r] = xsL[(mt * 16 + q * 4 + r) * 32 + (ts & 31)];
        float4v acc[2][2][4];
#pragma unroll
        for (int sp = 0; sp < 2; ++sp) {
            const int jj = (s0 + sp) * 16 + l15;
#pragma unroll
            for (int t = 0; t < 4; ++t) {
                const float bb = bwL[t * 256 + jj];
                const float wx = wwL[t * 256 + jj];
#pragma unroll
                for (int mt = 0; mt < 2; ++mt)
#pragma unroll
                    for (int r = 0; r < 4; ++r)
                        acc[mt][sp][t][r] = bb + xv[mt][r] * wx;
            }
        }

        half8 a0, a1;
        // kk=0: resident in LDS
        {
            a0 = AREAD(0, 0); a1 = AREAD(0, 1);
            const char* lb = smem + WRES_OFF + s0 * 4096 + lane * 16;
#pragma unroll
            for (int sp = 0; sp < 2; ++sp)
#pragma unroll
                for (int t = 0; t < 4; ++t) {
                    half8 bf = *(const half8*)(lb + sp * 4096 + t * 1024);
                    acc[0][sp][t] = __builtin_amdgcn_mfma_f32_16x16x32_f16(a0, bf, acc[0][sp][t], 0, 0, 0);
                    acc[1][sp][t] = __builtin_amdgcn_mfma_f32_16x16x32_f16(a1, bf, acc[1][sp][t], 0, 0, 0);
                }
        }
        // kk=1..7: streamed through the ring, 28 chunks, distance-3 prefetch
#pragma unroll
        for (int m = 0; m < 28; ++m) {
            const int kk = 1 + (m >> 2), t = m & 3, slot = m & 3;
            if (t == 0) { a0 = AREAD(kk, 0); a1 = AREAD(kk, 1); }
            WAIT_VM4();                                    // chunk m arrived
            half8 bf0 = *(const half8*)(ringR + slot * 8192);
            half8 bf1 = *(const half8*)(ringR + slot * 8192 + 512);
            acc[0][0][t] = __builtin_amdgcn_mfma_f32_16x16x32_f16(a0, bf0, acc[0][0][t], 0, 0, 0);
            acc[1][0][t] = __builtin_amdgcn_mfma_f32_16x16x32_f16(a1, bf0, acc[1][0][t], 0, 0, 0);
            acc[0][1][t] = __builtin_amdgcn_mfma_f32_16x16x32_f16(a0, bf1, acc[0][1][t], 0, 0, 0);
            acc[1][1][t] = __builtin_amdgcn_mfma_f32_16x16x32_f16(a1, bf1, acc[1][1][t], 0, 0, 0);
            {   // issue chunk m+3 (wraps into next step: weights step-invariant)
                int n = m + 3; if (n >= 28) n -= 28;
                const int kkn = 1 + (n >> 2), tn = n & 3, sn = n & 3;
#pragma unroll
                for (int sp = 0; sp < 2; ++sp)
                    stream_issue(wl + kkn * 65536 + sp * 4096 + tn * 1024,
                                 ringW + sn * RING_SLOT + sp * 1024);
            }
        }

        // gates + state update (lane owns rows mt*16+q*4+r, col (s0+sp)*16+l15)
        _Float16 hn[2][2][4];
#pragma unroll
        for (int mt = 0; mt < 2; ++mt)
#pragma unroll
            for (int sp = 0; sp < 2; ++sp)
#pragma unroll
                for (int r = 0; r < 4; ++r) {
                    float g  = ftanh(acc[mt][sp][0][r]);
                    float ii = fsig (acc[mt][sp][1][r]);
                    float f  = fsig (acc[mt][sp][2][r]);
                    float o  = fsig (acc[mt][sp][3][r]);
                    float cn = g * ii + cst[mt][sp][r] * f;
                    cst[mt][sp][r] = cn;
                    hn[mt][sp][r] = (_Float16)(ftanh(cn) * o);
                }

        BARRIER_LGKM();   // B1: all waves' A/B LDS reads of this step retired
#pragma unroll
        for (int mt = 0; mt < 2; ++mt)
#pragma unroll
            for (int sp = 0; sp < 2; ++sp)
#pragma unroll
                for (int r = 0; r < 4; ++r)
                    hf[mt * 4096 + wb + sp * 256 + r * 8] = hn[mt][sp][r];
        BARRIER_LGKM();   // B2: new h visible; ring DMAs stay in flight
    }

    // ---- epilogue: out = h_T @ W_ph + b_p ; wave wv handles rows 4wv..4wv+3 ----
#pragma unroll
    for (int rr = 0; rr < 4; ++rr) {
        int b = wv * 4 + rr;
        int mt = b >> 4, m = b & 15;
        float hv[4];
#pragma unroll
        for (int a = 0; a < 4; ++a) {
            int j = lane + a * 64;
            int idx = mt * 4096 + (j >> 5) * 512 + (((j >> 3) & 3) * 16 + m) * 8 + (j & 7);
            hv[a] = (float)hf[idx];
        }
#pragma unroll
        for (int c = 0; c < CC; ++c) {
            float sacc = 0.f;
#pragma unroll
            for (int a = 0; a < 4; ++a) sacc += hv[a] * Wp[(lane + a * 64) * CC + c];
#pragma unroll
            for (int off = 32; off > 0; off >>= 1) sacc += __shfl_xor(sacc, off, 64);
            if (lane == 0) out[(b0 + b) * CC + c] = sacc + bp[c];
        }
    }
}

extern "C" void kernel_launch(void* const* d_in, const int* in_sizes, int n_in,
                              void* d_out, int out_size, void* d_ws, size_t ws_size,
                              hipStream_t stream) {
    (void)in_sizes; (void)n_in; (void)out_size; (void)ws_size; // needs ws_size >= 524288
    const float* x   = (const float*)d_in[0];
    const float* Wgx = (const float*)d_in[1];
    const float* Wgh = (const float*)d_in[2];
    const float* Wix = (const float*)d_in[3];
    const float* Wih = (const float*)d_in[4];
    const float* Wfx = (const float*)d_in[5];
    const float* Wfh = (const float*)d_in[6];
    const float* Wox = (const float*)d_in[7];
    const float* Woh = (const float*)d_in[8];
    const float* Wp  = (const float*)d_in[9];
    const float* bg  = (const float*)d_in[10];
    const float* bi  = (const float*)d_in[11];
    const float* bf  = (const float*)d_in[12];
    const float* bo  = (const float*)d_in[13];
    const float* bp  = (const float*)d_in[14];
    _Float16* wsW = (_Float16*)d_ws;

    pack_weights<<<128, 256, 0, stream>>>(Wgh, Wih, Wfh, Woh, wsW);

    hipFuncSetAttribute((const void*)lstm_main,
                        hipFuncAttributeMaxDynamicSharedMemorySize, LDS_TOTAL);
    lstm_main<<<256, 512, LDS_TOTAL, stream>>>(
        x, wsW, Wgx, Wix, Wfx, Wox, bg, bi, bf, bo, Wp, bp, (float*)d_out);
}